// Round 16
// baseline (936.239 us; speedup 1.0000x reference)
//
#include <hip/hip_runtime.h>
#include <hip/hip_bf16.h>
#include <cstdio>

#define DEV static __device__ __forceinline__

typedef __attribute__((ext_vector_type(4))) float floatx4;
typedef __attribute__((ext_vector_type(8))) __bf16 bf16x8;

constexpr int Bv = 2, Tv = 512, Dv = 256, NHv = 4, Nv = 8192, NLv = 4, Vv = 256;
constexpr int BTv = Bv * Tv;   // 1024 rows (b,t)
constexpr int BHv = Bv * NHv;  // 8
constexpr float LNEPS = 1e-5f;
constexpr int KS_SC = 8;   // K-split for scores (K=8192 -> 1024 per block)
constexpr int KS_DEC = 8;  // K-split for decode (K=8192 -> 1024 per block)
constexpr int TILE = 128 * 32;  // shorts per LDS buffer

DEV float b2f(short s) {
    unsigned u = ((unsigned)(unsigned short)s) << 16;
    return __builtin_bit_cast(float, u);
}
DEV short f2b(float f) {  // RNE f32 -> bf16
    unsigned u = __builtin_bit_cast(unsigned, f);
    u = (u + 0x7fffu + ((u >> 16) & 1u)) >> 16;
    return (short)u;
}

typedef __attribute__((address_space(3))) unsigned int lds_u32;
typedef const __attribute__((address_space(1))) unsigned int glb_u32;
// async global->LDS, 16B per lane, whole wave writes ldsbase + lane*16
DEV void gload16(const short* g, short* ldsbase) {
    __builtin_amdgcn_global_load_lds((glb_u32*)g, (lds_u32*)ldsbase, 16, 0, 0);
}

// ---------------- transpose + f32->bf16 convert: in (R,C) -> out (C,R), per batch z
__global__ __launch_bounds__(256) void k_cvtT(const float* __restrict__ in,
                                              short* __restrict__ out, int R, int C) {
    __shared__ float tile[32][33];
    const float* ib = in + (size_t)blockIdx.z * R * C;
    short* ob = out + (size_t)blockIdx.z * R * C;
    int c0 = blockIdx.x * 32, r0 = blockIdx.y * 32;
    int tx = threadIdx.x & 31, ty = threadIdx.x >> 5;  // 32 x 8
#pragma unroll
    for (int i = 0; i < 4; i++) {
        int r = r0 + ty + i * 8;
        tile[ty + i * 8][tx] = ib[(size_t)r * C + c0 + tx];
    }
    __syncthreads();
#pragma unroll
    for (int i = 0; i < 4; i++) {
        int c = c0 + ty + i * 8;
        ob[(size_t)c * R + r0 + tx] = f2b(tile[tx][ty + i * 8]);
    }
}

// ---------------- bf16 transpose: xb (B*T, D) -> xbT [b][d][t]
__global__ __launch_bounds__(256) void k_transp(const short* __restrict__ xb,
                                                short* __restrict__ xbT) {
    __shared__ short tile[32][33];
    int b = blockIdx.z;
    int t0 = blockIdx.x * 32, d0 = blockIdx.y * 32;
    int tx = threadIdx.x & 31, ty = threadIdx.x >> 5;
#pragma unroll
    for (int i = 0; i < 4; i++)
        tile[ty + i * 8][tx] = xb[((size_t)b * Tv + t0 + ty + i * 8) * Dv + d0 + tx];
    __syncthreads();
#pragma unroll
    for (int i = 0; i < 4; i++)
        xbT[((size_t)b * Dv + d0 + ty + i * 8) * Tv + t0 + tx] = tile[tx][ty + i * 8];
}

// ---------------- rope table: (t, pair i) -> packed (bf16 cos | bf16 sin<<16)
__global__ __launch_bounds__(256) void k_rope(unsigned* __restrict__ tab) {
    int i = blockIdx.x * 256 + threadIdx.x;  // pair index 0..4095
    int t = blockIdx.y;
    float f = exp2f(-(float)i / 256.0f) * 0.15915494309189535f;
    float ph = fmodf((float)t * f, 1.0f) * 6.2831853071795864f;
    unsigned c = (unsigned short)f2b(cosf(ph));
    unsigned s = (unsigned short)f2b(sinf(ph));
    tab[(size_t)t * (Nv / 2) + i] = c | (s << 16);
}

// ---------------- block reduce (256 threads = 4 waves)
DEV void reduce2(float& s1, float& s2) {
    __shared__ float r1[4];
    __shared__ float r2[4];
#pragma unroll
    for (int o = 32; o > 0; o >>= 1) {
        s1 += __shfl_down(s1, o, 64);
        s2 += __shfl_down(s2, o, 64);
    }
    int lane = threadIdx.x & 63, w = threadIdx.x >> 6;
    if (lane == 0) { r1[w] = s1; r2[w] = s2; }
    __syncthreads();
    s1 = r1[0] + r1[1] + r1[2] + r1[3];
    s2 = r2[0] + r2[1] + r2[2] + r2[3];
}

DEV float ln_val(float v, float s1, float s2) {
    float m = s1 * (1.0f / Dv);
    float var = s2 * (1.0f / Dv) - m * m;
    float inv = rsqrtf(var + LNEPS);
    return (v - m) * inv;
}

// ---------------- embed lookup + LN -> x_f32, x_bf16
__global__ __launch_bounds__(256) void k_embed_ln(const int* __restrict__ idx,
                                                  const float* __restrict__ embed,
                                                  float* __restrict__ xf, short* __restrict__ xb) {
    int r = blockIdx.x, d = threadIdx.x;
    float v = embed[(size_t)idx[r] * Dv + d];
    float s1 = v, s2 = v * v;
    reduce2(s1, s2);
    float o = ln_val(v, s1, s2);
    xf[(size_t)r * Dv + d] = o;
    xb[(size_t)r * Dv + d] = f2b(o);
}

// ---------------- generic LN over D (no add): ykv f32 -> bf16
__global__ __launch_bounds__(256) void k_ln(const float* __restrict__ in,
                                            short* __restrict__ outb) {
    int r = blockIdx.x, d = threadIdx.x;
    size_t o = (size_t)r * Dv + d;
    float v = in[o];
    float s1 = v, s2 = v * v;
    reduce2(s1, s2);
    outb[o] = f2b(ln_val(v, s1, s2));
}

// ---------------- residual LN with 32-slab sum: x = LN(xf + sum_z ymb[z])
__global__ __launch_bounds__(256) void k_lnsum(const short* __restrict__ ymb,
                                               float* __restrict__ xf, short* __restrict__ xb) {
    int r = blockIdx.x, d = threadIdx.x;
    size_t o = (size_t)r * Dv + d;
    float v = xf[o];
#pragma unroll
    for (int z = 0; z < NHv * KS_DEC; z++)
        v += b2f(ymb[(size_t)z * BTv * Dv + o]);
    float s1 = v, s2 = v * v;
    reduce2(s1, s2);
    float res = ln_val(v, s1, s2);
    xf[o] = res;
    xb[o] = f2b(res);
}

// ---------------- MFMA 128x128 tile mainloop, double-buffered global_load_lds.
// LDS layout per buffer [128][32] shorts, chunk-XOR swizzled (src-permute == read-permute).
// 2-phase schedule: stage(t+1) issued BEFORE compute(t); one vmcnt+barrier per tile.
DEV void gemm_main(const short* __restrict__ Ab, int lda,
                   const short* __restrict__ Bb, int ldb, int K,
                   short* sA, short* sB, floatx4 acc[4][4]) {
    const int tid = threadIdx.x;
    const int lane = tid & 63, w = tid >> 6;
    const int wr = w >> 1, wc = w & 1;
    const int lrow = lane & 15;
    const int q = lane >> 4;                       // logical K-chunk of this lane
    const int rsw = (lrow >> 1) & 3;               // read swizzle selector
    const int srow = lane >> 2;                    // staged row within 16-row group
    const int ssw = (lane & 3) ^ ((lane >> 3) & 3);// staged logical chunk
    const int nt = K >> 5;
    // prologue: stage tile 0 into buffer 0
#pragma unroll
    for (int g2 = 0; g2 < 2; g2++) {
        int brow = g2 * 64 + w * 16;
        int grow = brow + srow;
        gload16(&Ab[(size_t)grow * lda + ssw * 8], &sA[brow * 32]);
        gload16(&Bb[(size_t)grow * ldb + ssw * 8], &sB[brow * 32]);
    }
    asm volatile("s_waitcnt vmcnt(0)" ::: "memory");
    __builtin_amdgcn_s_barrier();
    for (int t = 0; t < nt; t++) {
        const int cur = (t & 1) * TILE, nxt = ((t + 1) & 1) * TILE;
        if (t + 1 < nt) {
            int kk = (t + 1) * 32;
#pragma unroll
            for (int g2 = 0; g2 < 2; g2++) {
                int brow = g2 * 64 + w * 16;
                int grow = brow + srow;
                gload16(&Ab[(size_t)grow * lda + kk + ssw * 8], &sA[nxt + brow * 32]);
                gload16(&Bb[(size_t)grow * ldb + kk + ssw * 8], &sB[nxt + brow * 32]);
            }
        }
        bf16x8 aF[4], bF[4];
#pragma unroll
        for (int m = 0; m < 4; m++)
            aF[m] = *(const bf16x8*)&sA[cur + (wr * 64 + m * 16 + lrow) * 32 + ((q ^ rsw) * 8)];
#pragma unroll
        for (int n = 0; n < 4; n++)
            bF[n] = *(const bf16x8*)&sB[cur + (wc * 64 + n * 16 + lrow) * 32 + ((q ^ rsw) * 8)];
#pragma unroll
        for (int m = 0; m < 4; m++)
#pragma unroll
            for (int n = 0; n < 4; n++)
                acc[m][n] = __builtin_amdgcn_mfma_f32_16x16x32_bf16(aF[m], bF[n], acc[m][n], 0, 0, 0);
        // lgkmcnt(0): all ds_reads retired (regs loaded) before any wave re-stages this buffer
        asm volatile("s_waitcnt vmcnt(0) lgkmcnt(0)" ::: "memory");
        __builtin_amdgcn_s_barrier();
    }
}

// ---------------- layer GEMM 1 + fused rope: qr = rope(relu(x @ enc[h]))  (no xs write)
// XCD-aware: all 8 mb-blocks sharing a (nb,h) B-tile have same bid%8 -> same XCD L2.
__global__ __launch_bounds__(256) void k_latent(const short* __restrict__ xb,
                                                const short* __restrict__ encT,
                                                const unsigned* __restrict__ ropeT,
                                                short* __restrict__ qr) {
    __shared__ short sA[2 * TILE];
    __shared__ short sB[2 * TILE];
    int bid = blockIdx.x;                 // 2048 blocks
    int xcd = bid & 7, rr = bid >> 3;     // rr: 0..255
    int cmb = xcd + 8 * (rr & 31);        // (nb,h) combo 0..255, fixed per XCD
    int mb = rr >> 5;                     // 0..7
    int nb = cmb & 63, h = cmb >> 6;
    const short* Ab = xb + (size_t)mb * 128 * Dv;
    const short* Bb = encT + (size_t)h * Nv * Dv + (size_t)nb * 128 * Dv;
    floatx4 acc[4][4] = {};
    gemm_main(Ab, Dv, Bb, Dv, Dv, sA, sB, acc);
    int lane = threadIdx.x & 63, w = threadIdx.x >> 6, wr = w >> 1, wc = w & 1;
    int rb = (lane >> 4) * 4, cb = lane & 15;
    float sgn = (cb & 1) ? 1.0f : -1.0f;
#pragma unroll
    for (int m = 0; m < 4; m++)
#pragma unroll
        for (int n = 0; n < 4; n++) {
            int col = nb * 128 + wc * 64 + n * 16 + cb;
#pragma unroll
            for (int r = 0; r < 4; r++) {
                int row = mb * 128 + wr * 64 + m * 16 + rb + r;
                int b = row >> 9, t = row & 511;
                float v = acc[m][n][r];
                v = v > 0.f ? v : 0.f;
                float vp = __shfl_xor(v, 1);  // partner neuron in pair (cols 2i,2i+1)
                unsigned cs = ropeT[(size_t)t * (Nv / 2) + (col >> 1)];
                float c = b2f((short)(cs & 0xffff)), s = b2f((short)(cs >> 16));
                qr[((size_t)(b * NHv + h) * Tv + t) * Nv + col] = f2b(v * c + sgn * vp * s);
            }
        }
}

// ---------------- scores (K-split, slab output, NO atomics):
// scs[ks][bh][t][s] = partial qr[t,:].qr[s,:] over K-chunk ks, bf16
// XCD-aware: all 10 pb-blocks of one (bh,ks) share qr tiles on one XCD.
__global__ __launch_bounds__(256) void k_scores(const short* __restrict__ qr,
                                                short* __restrict__ scs) {
    __shared__ short sA[2 * TILE];
    __shared__ short sB[2 * TILE];
    int bid = blockIdx.x;                 // 640 blocks
    int xcd = bid & 7, rr = bid >> 3;     // rr: 0..79
    int cmb = xcd + 8 * (rr & 7);         // (bh,ks) combo 0..63
    int pb = rr >> 3;                     // 0..9
    int bh = cmb & 7, ks = cmb >> 3;
    int tb = 0;
    while (((tb + 1) * (tb + 2)) / 2 <= pb) tb++;
    int sb = pb - (tb * (tb + 1)) / 2;
    const bool diag = (tb == sb);
    const int KC = Nv / KS_SC;
    const short* Ab = qr + ((size_t)bh * Tv + tb * 128) * Nv + ks * KC;
    const short* Bb = qr + ((size_t)bh * Tv + sb * 128) * Nv + ks * KC;
    floatx4 acc[4][4] = {};
    const int tid = threadIdx.x, lane = tid & 63, w = tid >> 6;
    const int wr = w >> 1, wc = w & 1;
    const int lrow = lane & 15;
    const int q = lane >> 4;
    const int rsw = (lrow >> 1) & 3;
    const int srow = lane >> 2;
    const int ssw = (lane & 3) ^ ((lane >> 3) & 3);
    const int nt = KC >> 5;
    // prologue: stage tile 0 -> buffer 0
#pragma unroll
    for (int g2 = 0; g2 < 2; g2++) {
        int brow = g2 * 64 + w * 16;
        int grow = brow + srow;
        gload16(&Ab[(size_t)grow * Nv + ssw * 8], &sA[brow * 32]);
        if (!diag) gload16(&Bb[(size_t)grow * Nv + ssw * 8], &sB[brow * 32]);
    }
    asm volatile("s_waitcnt vmcnt(0)" ::: "memory");
    __builtin_amdgcn_s_barrier();
    for (int t = 0; t < nt; t++) {
        const int cur = (t & 1) * TILE, nxt = ((t + 1) & 1) * TILE;
        if (t + 1 < nt) {
            int kk = (t + 1) * 32;
#pragma unroll
            for (int g2 = 0; g2 < 2; g2++) {
                int brow = g2 * 64 + w * 16;
                int grow = brow + srow;
                gload16(&Ab[(size_t)grow * Nv + kk + ssw * 8], &sA[nxt + brow * 32]);
                if (!diag) gload16(&Bb[(size_t)grow * Nv + kk + ssw * 8], &sB[nxt + brow * 32]);
            }
        }
        const short* sBr = diag ? sA : sB;
        bf16x8 aF[4], bF[4];
#pragma unroll
        for (int m = 0; m < 4; m++)
            aF[m] = *(const bf16x8*)&sA[cur + (wr * 64 + m * 16 + lrow) * 32 + ((q ^ rsw) * 8)];
#pragma unroll
        for (int n = 0; n < 4; n++)
            bF[n] = *(const bf16x8*)&sBr[cur + (wc * 64 + n * 16 + lrow) * 32 + ((q ^ rsw) * 8)];
#pragma unroll
        for (int m = 0; m < 4; m++)
#pragma unroll
            for (int n = 0; n < 4; n++)
                acc[m][n] = __builtin_amdgcn_mfma_f32_16x16x32_bf16(aF[m], bF[n], acc[m][n], 0, 0, 0);
        asm volatile("s_waitcnt vmcnt(0) lgkmcnt(0)" ::: "memory");
        __builtin_amdgcn_s_barrier();
    }
    short* slab = scs + ((size_t)ks * BHv + bh) * Tv * Tv;
    int rb = (lane >> 4) * 4, cb = lane & 15;
#pragma unroll
    for (int m = 0; m < 4; m++)
#pragma unroll
        for (int n = 0; n < 4; n++)
#pragma unroll
            for (int r = 0; r < 4; r++) {
                int t = tb * 128 + wr * 64 + m * 16 + rb + r;
                int s = sb * 128 + wc * 64 + n * 16 + cb;
                slab[(size_t)t * Tv + s] = f2b(acc[m][n][r]);
            }
}

// ---------------- sum slabs + strict-lower mask -> scb (bf16)
__global__ __launch_bounds__(256) void k_redsc(const short* __restrict__ scs,
                                               short* __restrict__ scb) {
    int c = blockIdx.x * 256 + threadIdx.x;  // one 8-elem chunk
    int row = c >> 6;                        // bh*512 + t
    int s0 = (c & 63) * 8;
    int t = row & (Tv - 1);
    float a[8] = {};
#pragma unroll
    for (int ks = 0; ks < KS_SC; ks++) {
        int4 raw = *(const int4*)&scs[((size_t)ks * BHv * Tv + row) * Tv + s0];
        const short* rs = (const short*)&raw;
#pragma unroll
        for (int j = 0; j < 8; j++) a[j] += b2f(rs[j]);
    }
    union { short s[8]; int4 v; } u;
#pragma unroll
    for (int j = 0; j < 8; j++) u.s[j] = (s0 + j < t) ? f2b(a[j]) : 0;
    *(int4*)&scb[(size_t)row * Tv + s0] = u.v;
}

// ---------------- yKV = scb @ V via MFMA.  A = scb (bf16), B^T = xbT.
// Causal trim: scb upper-tri is zero, so K-loop stops at (mb+1)*128.
__global__ __launch_bounds__(256) void k_pvg(const short* __restrict__ scb,
                                             const short* __restrict__ xbT,
                                             float* __restrict__ ykv) {
    __shared__ short sA[2 * TILE];
    __shared__ short sB[2 * TILE];
    int mb = blockIdx.x, nb = blockIdx.y, bh = blockIdx.z;
    int b = bh >> 2;
    const short* Ab = scb + ((size_t)bh * Tv + mb * 128) * Tv;
    const short* Bb = xbT + ((size_t)b * Dv + nb * 128) * Tv;
    floatx4 acc[4][4] = {};
    gemm_main(Ab, Tv, Bb, Tv, (mb + 1) * 128, sA, sB, acc);
    int lane = threadIdx.x & 63, w = threadIdx.x >> 6, wr = w >> 1, wc = w & 1;
    int rb = (lane >> 4) * 4, cb = lane & 15;
#pragma unroll
    for (int m = 0; m < 4; m++)
#pragma unroll
        for (int n = 0; n < 4; n++)
#pragma unroll
            for (int r = 0; r < 4; r++) {
                int t = mb * 128 + wr * 64 + m * 16 + rb + r;
                int d = nb * 128 + wc * 64 + n * 16 + cb;
                ykv[((size_t)bh * Tv + t) * Dv + d] = acc[m][n][r];
            }
}

// ---------------- GEMM2 + gate: xy = relu(yKV_ln @ encv[h]) * invrope(qr)
// XCD-aware: all 8 (mb,b)-blocks sharing a (nb,h) encvT tile on one XCD.
__global__ __launch_bounds__(256) void k_gate(const short* __restrict__ ykvb,
                                              const short* __restrict__ encvT,
                                              const short* __restrict__ qr,
                                              const unsigned* __restrict__ ropeT,
                                              short* __restrict__ xy) {
    __shared__ short sA[2 * TILE];
    __shared__ short sB[2 * TILE];
    int bid = blockIdx.x;                 // 2048 blocks
    int xcd = bid & 7, rr = bid >> 3;     // rr: 0..255
    int cmb = xcd + 8 * (rr & 31);        // (nb,h) combo 0..255
    int wi = rr >> 5;                     // 0..7 = (mb,b)
    int mb = wi & 3, bq = wi >> 2;
    int nb = cmb & 63, h = cmb >> 6;
    int bh = bq * NHv + h;
    const short* Ab = ykvb + ((size_t)bh * Tv + mb * 128) * Dv;
    const short* Bb = encvT + (size_t)h * Nv * Dv + (size_t)nb * 128 * Dv;
    floatx4 acc[4][4] = {};
    gemm_main(Ab, Dv, Bb, Dv, Dv, sA, sB, acc);
    int lane = threadIdx.x & 63, w = threadIdx.x >> 6, wr = w >> 1, wc = w & 1;
    int rb = (lane >> 4) * 4, cb = lane & 15;
    int par = cb & 1;
    float sgn = par ? 1.0f : -1.0f;
#pragma unroll
    for (int m = 0; m < 4; m++)
#pragma unroll
        for (int n = 0; n < 4; n++) {
            int col = nb * 128 + wc * 64 + n * 16 + cb;
#pragma unroll
            for (int r = 0; r < 4; r++) {
                int t = mb * 128 + wr * 64 + m * 16 + rb + r;
                size_t idx = ((size_t)bh * Tv + t) * Nv + col;
                unsigned pq = *(const unsigned*)&qr[idx & ~(size_t)1];  // (even,odd) pair in one 4B load
                float qlo = b2f((short)(pq & 0xffff)), qhi2 = b2f((short)(pq >> 16));
                float qv = par ? qhi2 : qlo;
                float qp = par ? qlo : qhi2;
                unsigned cs = ropeT[(size_t)t * (Nv / 2) + (col >> 1)];
                float c = b2f((short)(cs & 0xffff)), s = b2f((short)(cs >> 16));
                float xsr = qv * c - sgn * qp * s;  // inverse rotation = x_sparse
                float v = acc[m][n][r];
                v = v > 0.f ? v : 0.f;
                xy[idx] = f2b(v * xsr);
            }
        }
}

// ---------------- decode (K-split=8, slab output, NO atomics):
// ymb[z=(h*KS+ks)][row][d] = partial xy[h] @ dec[h], bf16
// XCD-aware: 8 mb-blocks sharing a (nb,h,ks) decT panel on one XCD.  512 blocks.
__global__ __launch_bounds__(256) void k_decode(const short* __restrict__ xy,
                                                const short* __restrict__ decT,
                                                short* __restrict__ ymb) {
    __shared__ short sA[2 * TILE];
    __shared__ short sB[2 * TILE];
    int bid = blockIdx.x;                 // 512 blocks
    int xcd = bid & 7, rr = bid >> 3;     // rr: 0..63
    int cmb = xcd + 8 * (rr & 7);         // (nb,h,ks) combo 0..63
    int mb = rr >> 3;                     // 0..7
    int nb = cmb & 1, h = (cmb >> 1) & 3, ks = cmb >> 3;
    const int KC = Nv / KS_DEC;           // 1024
    int row0 = mb * 128;
    int b = row0 >> 9, t0 = row0 & 511;
    const short* Ab = xy + ((size_t)(b * NHv + h) * Tv + t0) * Nv + ks * KC;
    const short* Bb = decT + (size_t)h * Dv * Nv + (size_t)nb * 128 * Nv + ks * KC;
    floatx4 acc[4][4] = {};
    gemm_main(Ab, Nv, Bb, Nv, KC, sA, sB, acc);
    short* slab = ymb + (size_t)(h * KS_DEC + ks) * BTv * Dv;
    int lane = threadIdx.x & 63, w = threadIdx.x >> 6, wr = w >> 1, wc = w & 1;
    int rb = (lane >> 4) * 4, cb = lane & 15;
#pragma unroll
    for (int m = 0; m < 4; m++)
#pragma unroll
        for (int n = 0; n < 4; n++)
#pragma unroll
            for (int r = 0; r < 4; r++) {
                int row = row0 + wr * 64 + m * 16 + rb + r;
                int col = nb * 128 + wc * 64 + n * 16 + cb;
                slab[(size_t)row * Dv + col] = f2b(acc[m][n][r]);
            }
}

// ---------------- final head: out = x @ lm_head
__global__ __launch_bounds__(256) void k_head(const short* __restrict__ xb,
                                              const short* __restrict__ lmhT,
                                              float* __restrict__ out) {
    __shared__ short sA[2 * TILE];
    __shared__ short sB[2 * TILE];
    int mb = blockIdx.x, nb = blockIdx.y;
    const short* Ab = xb + (size_t)mb * 128 * Dv;
    const short* Bb = lmhT + (size_t)nb * 128 * Dv;
    floatx4 acc[4][4] = {};
    gemm_main(Ab, Dv, Bb, Dv, Dv, sA, sB, acc);
    int lane = threadIdx.x & 63, w = threadIdx.x >> 6, wr = w >> 1, wc = w & 1;
    int rb = (lane >> 4) * 4, cb = lane & 15;
#pragma unroll
    for (int m = 0; m < 4; m++)
#pragma unroll
        for (int n = 0; n < 4; n++)
#pragma unroll
            for (int r = 0; r < 4; r++) {
                int row = mb * 128 + wr * 64 + m * 16 + rb + r;
                int col = nb * 128 + wc * 64 + n * 16 + cb;
                out[(size_t)row * Vv + col] = acc[m][n][r];
            }
}

extern "C" void kernel_launch(void* const* d_in, const int* in_sizes, int n_in,
                              void* d_out, int out_size, void* d_ws, size_t ws_size,
                              hipStream_t stream) {
    const int* idx = (const int*)d_in[0];
    const float* embed = (const float*)d_in[1];
    const float* enc = (const float*)d_in[2];
    const float* encv = (const float*)d_in[3];
    const float* dec = (const float*)d_in[4];
    const float* lmh = (const float*)d_in[5];
    float* out = (float*)d_out;

    char* w = (char*)d_ws;
    size_t off = 0;
    auto alloc = [&](size_t bytes) -> void* {
        void* p = w + off;
        off = (off + bytes + 255) & ~(size_t)255;
        return p;
    };
    short* encT = (short*)alloc((size_t)NHv * Nv * Dv * 2);
    short* encvT = (short*)alloc((size_t)NHv * Nv * Dv * 2);
    short* decT = (short*)alloc((size_t)NHv * Dv * Nv * 2);
    short* lmhT = (short*)alloc((size_t)Vv * Dv * 2);
    unsigned* ropeT = (unsigned*)alloc((size_t)Tv * (Nv / 2) * 4);
    float* xf = (float*)alloc((size_t)BTv * Dv * 4);
    short* xb = (short*)alloc((size_t)BTv * Dv * 2);
    short* xbT = (short*)alloc((size_t)BTv * Dv * 2);
    short* xy = (short*)alloc((size_t)BHv * Tv * Nv * 2);
    short* qr = (short*)alloc((size_t)BHv * Tv * Nv * 2);
    short* scs = (short*)alloc((size_t)KS_SC * BHv * Tv * Tv * 2);   // score slabs (bf16)
    short* scb = (short*)alloc((size_t)BHv * Tv * Tv * 2);           // reduced masked scores
    float* ykvf = (float*)alloc((size_t)BHv * Tv * Dv * 4);
    short* ykvb = (short*)alloc((size_t)BHv * Tv * Dv * 2);
    short* ymb = (short*)alloc((size_t)NHv * KS_DEC * BTv * Dv * 2); // decode slabs (bf16)
    if (off > ws_size) {
        fprintf(stderr, "BDH: workspace too small: need %zu, have %zu\n", off, ws_size);
        return;
    }

    // one-time prep (per call): bf16 transposed weights + rope table + x0
    k_cvtT<<<dim3(Nv / 32, Dv / 32, NHv), 256, 0, stream>>>(enc, encT, Dv, Nv);
    k_cvtT<<<dim3(Nv / 32, Dv / 32, NHv), 256, 0, stream>>>(encv, encvT, Dv, Nv);
    k_cvtT<<<dim3(Dv / 32, Nv / 32, NHv), 256, 0, stream>>>(dec, decT, Nv, Dv);
    k_cvtT<<<dim3(Vv / 32, Dv / 32, 1), 256, 0, stream>>>(lmh, lmhT, Dv, Vv);
    k_rope<<<dim3(Nv / 2 / 256, Tv), 256, 0, stream>>>(ropeT);
    k_embed_ln<<<BTv, 256, 0, stream>>>(idx, embed, xf, xb);

    for (int L = 0; L < NLv; L++) {
        k_latent<<<2048, 256, 0, stream>>>(xb, encT, ropeT, qr);
        k_transp<<<dim3(Tv / 32, Dv / 32, Bv), 256, 0, stream>>>(xb, xbT);
        k_scores<<<640, 256, 0, stream>>>(qr, scs);
        k_redsc<<<(BHv * Tv * Tv / 8) / 256, 256, 0, stream>>>(scs, scb);
        k_pvg<<<dim3(Tv / 128, Dv / 128, BHv), 256, 0, stream>>>(scb, xbT, ykvf);
        k_ln<<<BHv * Tv, 256, 0, stream>>>(ykvf, ykvb);
        k_gate<<<2048, 256, 0, stream>>>(ykvb, encvT, qr, ropeT, xy);
        k_decode<<<512, 256, 0, stream>>>(xy, decT, ymb);
        k_lnsum<<<BTv, 256, 0, stream>>>(ymb, xf, xb);
    }
    k_head<<<dim3(BTv / 128, Vv / 128), 256, 0, stream>>>(xb, lmhT, out);
}

// Round 19
// 763.509 us; speedup vs baseline: 1.2262x; 1.2262x over previous
//
#include <hip/hip_runtime.h>
#include <hip/hip_bf16.h>
#include <cstdio>

#define DEV static __device__ __forceinline__

typedef __attribute__((ext_vector_type(4))) float floatx4;
typedef __attribute__((ext_vector_type(8))) __bf16 bf16x8;

constexpr int Bv = 2, Tv = 512, Dv = 256, NHv = 4, Nv = 8192, NLv = 4, Vv = 256;
constexpr int BTv = Bv * Tv;   // 1024 rows (b,t)
constexpr int BHv = Bv * NHv;  // 8
constexpr float LNEPS = 1e-5f;
constexpr int KS_SC = 8;   // K-split for scores (K=8192 -> 1024 per block)
constexpr int KS_DEC = 8;  // K-split for decode (K=8192 -> 1024 per block)

DEV float b2f(short s) {
    unsigned u = ((unsigned)(unsigned short)s) << 16;
    return __builtin_bit_cast(float, u);
}
DEV short f2b(float f) {  // RNE f32 -> bf16
    unsigned u = __builtin_bit_cast(unsigned, f);
    u = (u + 0x7fffu + ((u >> 16) & 1u)) >> 16;
    return (short)u;
}

typedef __attribute__((address_space(3))) unsigned int lds_u32;
typedef const __attribute__((address_space(1))) unsigned int glb_u32;
// async global->LDS, 16B per lane, whole wave writes ldsbase + lane*16
DEV void gload16(const short* g, short* ldsbase) {
    __builtin_amdgcn_global_load_lds((glb_u32*)g, (lds_u32*)ldsbase, 16, 0, 0);
}

// ---------------- transpose + f32->bf16 convert: in (R,C) -> out (C,R), per batch z
__global__ __launch_bounds__(256) void k_cvtT(const float* __restrict__ in,
                                              short* __restrict__ out, int R, int C) {
    __shared__ float tile[32][33];
    const float* ib = in + (size_t)blockIdx.z * R * C;
    short* ob = out + (size_t)blockIdx.z * R * C;
    int c0 = blockIdx.x * 32, r0 = blockIdx.y * 32;
    int tx = threadIdx.x & 31, ty = threadIdx.x >> 5;  // 32 x 8
#pragma unroll
    for (int i = 0; i < 4; i++) {
        int r = r0 + ty + i * 8;
        tile[ty + i * 8][tx] = ib[(size_t)r * C + c0 + tx];
    }
    __syncthreads();
#pragma unroll
    for (int i = 0; i < 4; i++) {
        int c = c0 + ty + i * 8;
        ob[(size_t)c * R + r0 + tx] = f2b(tile[tx][ty + i * 8]);
    }
}

// ---------------- bf16 transpose: xb (B*T, D) -> xbT [b][d][t]
__global__ __launch_bounds__(256) void k_transp(const short* __restrict__ xb,
                                                short* __restrict__ xbT) {
    __shared__ short tile[32][33];
    int b = blockIdx.z;
    int t0 = blockIdx.x * 32, d0 = blockIdx.y * 32;
    int tx = threadIdx.x & 31, ty = threadIdx.x >> 5;
#pragma unroll
    for (int i = 0; i < 4; i++)
        tile[ty + i * 8][tx] = xb[((size_t)b * Tv + t0 + ty + i * 8) * Dv + d0 + tx];
    __syncthreads();
#pragma unroll
    for (int i = 0; i < 4; i++)
        xbT[((size_t)b * Dv + d0 + ty + i * 8) * Tv + t0 + tx] = tile[tx][ty + i * 8];
}

// ---------------- rope table: (t, pair i) -> packed (bf16 cos | bf16 sin<<16)
__global__ __launch_bounds__(256) void k_rope(unsigned* __restrict__ tab) {
    int i = blockIdx.x * 256 + threadIdx.x;  // pair index 0..4095
    int t = blockIdx.y;
    float f = exp2f(-(float)i / 256.0f) * 0.15915494309189535f;
    float ph = fmodf((float)t * f, 1.0f) * 6.2831853071795864f;
    unsigned c = (unsigned short)f2b(cosf(ph));
    unsigned s = (unsigned short)f2b(sinf(ph));
    tab[(size_t)t * (Nv / 2) + i] = c | (s << 16);
}

// ---------------- block reduce (256 threads = 4 waves)
DEV void reduce2(float& s1, float& s2) {
    __shared__ float r1[4];
    __shared__ float r2[4];
#pragma unroll
    for (int o = 32; o > 0; o >>= 1) {
        s1 += __shfl_down(s1, o, 64);
        s2 += __shfl_down(s2, o, 64);
    }
    int lane = threadIdx.x & 63, w = threadIdx.x >> 6;
    if (lane == 0) { r1[w] = s1; r2[w] = s2; }
    __syncthreads();
    s1 = r1[0] + r1[1] + r1[2] + r1[3];
    s2 = r2[0] + r2[1] + r2[2] + r2[3];
}

DEV float ln_val(float v, float s1, float s2) {
    float m = s1 * (1.0f / Dv);
    float var = s2 * (1.0f / Dv) - m * m;
    float inv = rsqrtf(var + LNEPS);
    return (v - m) * inv;
}

// ---------------- embed lookup + LN -> x_f32, x_bf16
__global__ __launch_bounds__(256) void k_embed_ln(const int* __restrict__ idx,
                                                  const float* __restrict__ embed,
                                                  float* __restrict__ xf, short* __restrict__ xb) {
    int r = blockIdx.x, d = threadIdx.x;
    float v = embed[(size_t)idx[r] * Dv + d];
    float s1 = v, s2 = v * v;
    reduce2(s1, s2);
    float o = ln_val(v, s1, s2);
    xf[(size_t)r * Dv + d] = o;
    xb[(size_t)r * Dv + d] = f2b(o);
}

// ---------------- LN over D, bf16 in -> bf16 out
__global__ __launch_bounds__(256) void k_ln(const short* __restrict__ in,
                                            short* __restrict__ outb) {
    int r = blockIdx.x, d = threadIdx.x;
    size_t o = (size_t)r * Dv + d;
    float v = b2f(in[o]);
    float s1 = v, s2 = v * v;
    reduce2(s1, s2);
    outb[o] = f2b(ln_val(v, s1, s2));
}

// ---------------- residual LN with 32-slab sum: x = LN(xf + sum_z ymb[z])
__global__ __launch_bounds__(256) void k_lnsum(const short* __restrict__ ymb,
                                               float* __restrict__ xf, short* __restrict__ xb) {
    int r = blockIdx.x, d = threadIdx.x;
    size_t o = (size_t)r * Dv + d;
    float v = xf[o];
#pragma unroll
    for (int z = 0; z < NHv * KS_DEC; z++)
        v += b2f(ymb[(size_t)z * BTv * Dv + o]);
    float s1 = v, s2 = v * v;
    reduce2(s1, s2);
    float res = ln_val(v, s1, s2);
    xf[o] = res;
    xb[o] = f2b(res);
}

// ---------------- MFMA 128x128 tile mainloop with global_load_lds staging.
// LDS layout [128][32] shorts, chunk-XOR swizzled: physical 16B-chunk cp of row r
// holds logical chunk cp ^ ((r>>1)&3).  Source-permute == read-permute (involution).
DEV void gemm_main(const short* __restrict__ Ab, int lda,
                   const short* __restrict__ Bb, int ldb, int K,
                   short* sA, short* sB, floatx4 acc[4][4]) {
    const int tid = threadIdx.x;
    const int lane = tid & 63, w = tid >> 6;
    const int wr = w >> 1, wc = w & 1;
    const int lrow = lane & 15;
    const int q = lane >> 4;                       // logical K-chunk of this lane
    const int rsw = (lrow >> 1) & 3;               // read swizzle selector
    const int srow = lane >> 2;                    // staged row within 16-row group
    const int ssw = (lane & 3) ^ ((lane >> 3) & 3);// staged logical chunk
    for (int kk = 0; kk < K; kk += 32) {
        __syncthreads();
#pragma unroll
        for (int g2 = 0; g2 < 2; g2++) {
            int brow = g2 * 64 + w * 16;           // wave-uniform base row
            int grow = brow + srow;
            gload16(&Ab[(size_t)grow * lda + kk + ssw * 8], &sA[brow * 32]);
            gload16(&Bb[(size_t)grow * ldb + kk + ssw * 8], &sB[brow * 32]);
        }
        __syncthreads();                           // drains vmcnt -> LDS ready
        bf16x8 aF[4], bF[4];
#pragma unroll
        for (int m = 0; m < 4; m++)
            aF[m] = *(const bf16x8*)&sA[(wr * 64 + m * 16 + lrow) * 32 + ((q ^ rsw) * 8)];
#pragma unroll
        for (int n = 0; n < 4; n++)
            bF[n] = *(const bf16x8*)&sB[(wc * 64 + n * 16 + lrow) * 32 + ((q ^ rsw) * 8)];
#pragma unroll
        for (int m = 0; m < 4; m++)
#pragma unroll
            for (int n = 0; n < 4; n++)
                acc[m][n] = __builtin_amdgcn_mfma_f32_16x16x32_bf16(aF[m], bF[n], acc[m][n], 0, 0, 0);
    }
}

// ---------------- layer GEMM 1 + fused rope: qr = rope(relu(x @ enc[h]))  (no xs write)
// XCD-aware: all 8 mb-blocks sharing a (nb,h) B-tile have same bid%8 -> same XCD L2.
__global__ __launch_bounds__(256) void k_latent(const short* __restrict__ xb,
                                                const short* __restrict__ encT,
                                                const unsigned* __restrict__ ropeT,
                                                short* __restrict__ qr) {
    __shared__ short sA[128 * 32];
    __shared__ short sB[128 * 32];
    int bid = blockIdx.x;                 // 2048 blocks
    int xcd = bid & 7, rr = bid >> 3;     // rr: 0..255
    int cmb = xcd + 8 * (rr & 31);        // (nb,h) combo 0..255, fixed per XCD
    int mb = rr >> 5;                     // 0..7
    int nb = cmb & 63, h = cmb >> 6;
    const short* Ab = xb + (size_t)mb * 128 * Dv;
    const short* Bb = encT + (size_t)h * Nv * Dv + (size_t)nb * 128 * Dv;
    floatx4 acc[4][4] = {};
    gemm_main(Ab, Dv, Bb, Dv, Dv, sA, sB, acc);
    int lane = threadIdx.x & 63, w = threadIdx.x >> 6, wr = w >> 1, wc = w & 1;
    int rb = (lane >> 4) * 4, cb = lane & 15;
    float sgn = (cb & 1) ? 1.0f : -1.0f;
#pragma unroll
    for (int m = 0; m < 4; m++)
#pragma unroll
        for (int n = 0; n < 4; n++) {
            int col = nb * 128 + wc * 64 + n * 16 + cb;
#pragma unroll
            for (int r = 0; r < 4; r++) {
                int row = mb * 128 + wr * 64 + m * 16 + rb + r;
                int b = row >> 9, t = row & 511;
                float v = acc[m][n][r];
                v = v > 0.f ? v : 0.f;
                float vp = __shfl_xor(v, 1);  // partner neuron in pair (cols 2i,2i+1)
                unsigned cs = ropeT[(size_t)t * (Nv / 2) + (col >> 1)];
                float c = b2f((short)(cs & 0xffff)), s = b2f((short)(cs >> 16));
                qr[((size_t)(b * NHv + h) * Tv + t) * Nv + col] = f2b(v * c + sgn * vp * s);
            }
        }
}

// ---------------- scores (K-split, slab output, NO atomics):
// scs[ks][bh][t][s] = partial qr[t,:].qr[s,:] over K-chunk ks, bf16
// XCD-aware: all 10 pb-blocks of one (bh,ks) share qr tiles on one XCD.
__global__ __launch_bounds__(256) void k_scores(const short* __restrict__ qr,
                                                short* __restrict__ scs) {
    __shared__ short sA[128 * 32];
    __shared__ short sB[128 * 32];
    int bid = blockIdx.x;                 // 640 blocks
    int xcd = bid & 7, rr = bid >> 3;     // rr: 0..79
    int cmb = xcd + 8 * (rr & 7);         // (bh,ks) combo 0..63
    int pb = rr >> 3;                     // 0..9
    int bh = cmb & 7, ks = cmb >> 3;
    int tb = 0;
    while (((tb + 1) * (tb + 2)) / 2 <= pb) tb++;
    int sb = pb - (tb * (tb + 1)) / 2;
    const bool diag = (tb == sb);
    const int KC = Nv / KS_SC;
    const short* Ab = qr + ((size_t)bh * Tv + tb * 128) * Nv + ks * KC;
    const short* Bb = qr + ((size_t)bh * Tv + sb * 128) * Nv + ks * KC;
    floatx4 acc[4][4] = {};
    const int tid = threadIdx.x, lane = tid & 63, w = tid >> 6;
    const int wr = w >> 1, wc = w & 1;
    const int lrow = lane & 15;
    const int q = lane >> 4;
    const int rsw = (lrow >> 1) & 3;
    const int srow = lane >> 2;
    const int ssw = (lane & 3) ^ ((lane >> 3) & 3);
    for (int kk = 0; kk < KC; kk += 32) {
        __syncthreads();
#pragma unroll
        for (int g2 = 0; g2 < 2; g2++) {
            int brow = g2 * 64 + w * 16;
            int grow = brow + srow;
            gload16(&Ab[(size_t)grow * Nv + kk + ssw * 8], &sA[brow * 32]);
            if (!diag)
                gload16(&Bb[(size_t)grow * Nv + kk + ssw * 8], &sB[brow * 32]);
        }
        __syncthreads();
        const short* sBr = diag ? sA : sB;
        bf16x8 aF[4], bF[4];
#pragma unroll
        for (int m = 0; m < 4; m++)
            aF[m] = *(const bf16x8*)&sA[(wr * 64 + m * 16 + lrow) * 32 + ((q ^ rsw) * 8)];
#pragma unroll
        for (int n = 0; n < 4; n++)
            bF[n] = *(const bf16x8*)&sBr[(wc * 64 + n * 16 + lrow) * 32 + ((q ^ rsw) * 8)];
#pragma unroll
        for (int m = 0; m < 4; m++)
#pragma unroll
            for (int n = 0; n < 4; n++)
                acc[m][n] = __builtin_amdgcn_mfma_f32_16x16x32_bf16(aF[m], bF[n], acc[m][n], 0, 0, 0);
    }
    short* slab = scs + ((size_t)ks * BHv + bh) * Tv * Tv;
    int rb = (lane >> 4) * 4, cb = lane & 15;
#pragma unroll
    for (int m = 0; m < 4; m++)
#pragma unroll
        for (int n = 0; n < 4; n++)
#pragma unroll
            for (int r = 0; r < 4; r++) {
                int t = tb * 128 + wr * 64 + m * 16 + rb + r;
                int s = sb * 128 + wc * 64 + n * 16 + cb;
                slab[(size_t)t * Tv + s] = f2b(acc[m][n][r]);
            }
}

// ---------------- sum slabs + strict-lower mask -> scb (bf16)
__global__ __launch_bounds__(256) void k_redsc(const short* __restrict__ scs,
                                               short* __restrict__ scb) {
    int c = blockIdx.x * 256 + threadIdx.x;  // one 8-elem chunk
    int row = c >> 6;                        // bh*512 + t
    int s0 = (c & 63) * 8;
    int t = row & (Tv - 1);
    float a[8] = {};
#pragma unroll
    for (int ks = 0; ks < KS_SC; ks++) {
        int4 raw = *(const int4*)&scs[((size_t)ks * BHv * Tv + row) * Tv + s0];
        const short* rs = (const short*)&raw;
#pragma unroll
        for (int j = 0; j < 8; j++) a[j] += b2f(rs[j]);
    }
    union { short s[8]; int4 v; } u;
#pragma unroll
    for (int j = 0; j < 8; j++) u.s[j] = (s0 + j < t) ? f2b(a[j]) : 0;
    *(int4*)&scb[(size_t)row * Tv + s0] = u.v;
}

// ---------------- yKV = scb @ V via MFMA.  A = scb (bf16), B^T = xbT.
// Causal trim: scb upper-tri is zero, so K-loop stops at (mb+1)*128.  Writes bf16.
__global__ __launch_bounds__(256) void k_pvg(const short* __restrict__ scb,
                                             const short* __restrict__ xbT,
                                             short* __restrict__ ykvh) {
    __shared__ short sA[128 * 32];
    __shared__ short sB[128 * 32];
    int mb = blockIdx.x, nb = blockIdx.y, bh = blockIdx.z;
    int b = bh >> 2;
    const short* Ab = scb + ((size_t)bh * Tv + mb * 128) * Tv;
    const short* Bb = xbT + ((size_t)b * Dv + nb * 128) * Tv;
    floatx4 acc[4][4] = {};
    gemm_main(Ab, Tv, Bb, Tv, (mb + 1) * 128, sA, sB, acc);
    int lane = threadIdx.x & 63, w = threadIdx.x >> 6, wr = w >> 1, wc = w & 1;
    int rb = (lane >> 4) * 4, cb = lane & 15;
#pragma unroll
    for (int m = 0; m < 4; m++)
#pragma unroll
        for (int n = 0; n < 4; n++)
#pragma unroll
            for (int r = 0; r < 4; r++) {
                int t = mb * 128 + wr * 64 + m * 16 + rb + r;
                int d = nb * 128 + wc * 64 + n * 16 + cb;
                ykvh[((size_t)bh * Tv + t) * Dv + d] = f2b(acc[m][n][r]);
            }
}

// ---------------- GEMM2 + gate: xy = relu(yKV_ln @ encv[h]) * invrope(qr)
// XCD-aware: all 8 (mb,b)-blocks sharing a (nb,h) encvT tile on one XCD.
__global__ __launch_bounds__(256) void k_gate(const short* __restrict__ ykvb,
                                              const short* __restrict__ encvT,
                                              const short* __restrict__ qr,
                                              const unsigned* __restrict__ ropeT,
                                              short* __restrict__ xy) {
    __shared__ short sA[128 * 32];
    __shared__ short sB[128 * 32];
    int bid = blockIdx.x;                 // 2048 blocks
    int xcd = bid & 7, rr = bid >> 3;     // rr: 0..255
    int cmb = xcd + 8 * (rr & 31);        // (nb,h) combo 0..255
    int wi = rr >> 5;                     // 0..7 = (mb,b)
    int mb = wi & 3, bq = wi >> 2;
    int nb = cmb & 63, h = cmb >> 6;
    int bh = bq * NHv + h;
    const short* Ab = ykvb + ((size_t)bh * Tv + mb * 128) * Dv;
    const short* Bb = encvT + (size_t)h * Nv * Dv + (size_t)nb * 128 * Dv;
    floatx4 acc[4][4] = {};
    gemm_main(Ab, Dv, Bb, Dv, Dv, sA, sB, acc);
    int lane = threadIdx.x & 63, w = threadIdx.x >> 6, wr = w >> 1, wc = w & 1;
    int rb = (lane >> 4) * 4, cb = lane & 15;
    int par = cb & 1;
    float sgn = par ? 1.0f : -1.0f;
#pragma unroll
    for (int m = 0; m < 4; m++)
#pragma unroll
        for (int n = 0; n < 4; n++) {
            int col = nb * 128 + wc * 64 + n * 16 + cb;
#pragma unroll
            for (int r = 0; r < 4; r++) {
                int t = mb * 128 + wr * 64 + m * 16 + rb + r;
                size_t idx = ((size_t)bh * Tv + t) * Nv + col;
                unsigned pq = *(const unsigned*)&qr[idx & ~(size_t)1];  // (even,odd) pair in one 4B load
                float qlo = b2f((short)(pq & 0xffff)), qhi2 = b2f((short)(pq >> 16));
                float qv = par ? qhi2 : qlo;
                float qp = par ? qlo : qhi2;
                unsigned cs = ropeT[(size_t)t * (Nv / 2) + (col >> 1)];
                float c = b2f((short)(cs & 0xffff)), s = b2f((short)(cs >> 16));
                float xsr = qv * c - sgn * qp * s;  // inverse rotation = x_sparse
                float v = acc[m][n][r];
                v = v > 0.f ? v : 0.f;
                xy[idx] = f2b(v * xsr);
            }
        }
}

// ---------------- decode (K-split=8, slab output, NO atomics):
// ymb[z=(h*KS+ks)][row][d] = partial xy[h] @ dec[h], bf16
// XCD-aware: 8 mb-blocks sharing a (nb,h,ks) decT panel on one XCD.  512 blocks.
__global__ __launch_bounds__(256) void k_decode(const short* __restrict__ xy,
                                                const short* __restrict__ decT,
                                                short* __restrict__ ymb) {
    __shared__ short sA[128 * 32];
    __shared__ short sB[128 * 32];
    int bid = blockIdx.x;                 // 512 blocks
    int xcd = bid & 7, rr = bid >> 3;     // rr: 0..63
    int cmb = xcd + 8 * (rr & 7);         // (nb,h,ks) combo 0..63
    int mb = rr >> 3;                     // 0..7
    int nb = cmb & 1, h = (cmb >> 1) & 3, ks = cmb >> 3;
    const int KC = Nv / KS_DEC;           // 1024
    int row0 = mb * 128;
    int b = row0 >> 9, t0 = row0 & 511;
    const short* Ab = xy + ((size_t)(b * NHv + h) * Tv + t0) * Nv + ks * KC;
    const short* Bb = decT + (size_t)h * Dv * Nv + (size_t)nb * 128 * Nv + ks * KC;
    floatx4 acc[4][4] = {};
    gemm_main(Ab, Nv, Bb, Nv, KC, sA, sB, acc);
    short* slab = ymb + (size_t)(h * KS_DEC + ks) * BTv * Dv;
    int lane = threadIdx.x & 63, w = threadIdx.x >> 6, wr = w >> 1, wc = w & 1;
    int rb = (lane >> 4) * 4, cb = lane & 15;
#pragma unroll
    for (int m = 0; m < 4; m++)
#pragma unroll
        for (int n = 0; n < 4; n++)
#pragma unroll
            for (int r = 0; r < 4; r++) {
                int row = row0 + wr * 64 + m * 16 + rb + r;
                int col = nb * 128 + wc * 64 + n * 16 + cb;
                slab[(size_t)row * Dv + col] = f2b(acc[m][n][r]);
            }
}

// ---------------- final head: out = x @ lm_head
__global__ __launch_bounds__(256) void k_head(const short* __restrict__ xb,
                                              const short* __restrict__ lmhT,
                                              float* __restrict__ out) {
    __shared__ short sA[128 * 32];
    __shared__ short sB[128 * 32];
    int mb = blockIdx.x, nb = blockIdx.y;
    const short* Ab = xb + (size_t)mb * 128 * Dv;
    const short* Bb = lmhT + (size_t)nb * 128 * Dv;
    floatx4 acc[4][4] = {};
    gemm_main(Ab, Dv, Bb, Dv, Dv, sA, sB, acc);
    int lane = threadIdx.x & 63, w = threadIdx.x >> 6, wr = w >> 1, wc = w & 1;
    int rb = (lane >> 4) * 4, cb = lane & 15;
#pragma unroll
    for (int m = 0; m < 4; m++)
#pragma unroll
        for (int n = 0; n < 4; n++)
#pragma unroll
            for (int r = 0; r < 4; r++) {
                int row = mb * 128 + wr * 64 + m * 16 + rb + r;
                int col = nb * 128 + wc * 64 + n * 16 + cb;
                out[(size_t)row * Vv + col] = acc[m][n][r];
            }
}

extern "C" void kernel_launch(void* const* d_in, const int* in_sizes, int n_in,
                              void* d_out, int out_size, void* d_ws, size_t ws_size,
                              hipStream_t stream) {
    const int* idx = (const int*)d_in[0];
    const float* embed = (const float*)d_in[1];
    const float* enc = (const float*)d_in[2];
    const float* encv = (const float*)d_in[3];
    const float* dec = (const float*)d_in[4];
    const float* lmh = (const float*)d_in[5];
    float* out = (float*)d_out;

    char* w = (char*)d_ws;
    size_t off = 0;
    auto alloc = [&](size_t bytes) -> void* {
        void* p = w + off;
        off = (off + bytes + 255) & ~(size_t)255;
        return p;
    };
    short* encT = (short*)alloc((size_t)NHv * Nv * Dv * 2);
    short* encvT = (short*)alloc((size_t)NHv * Nv * Dv * 2);
    short* decT = (short*)alloc((size_t)NHv * Dv * Nv * 2);
    short* lmhT = (short*)alloc((size_t)Vv * Dv * 2);
    unsigned* ropeT = (unsigned*)alloc((size_t)Tv * (Nv / 2) * 4);
    float* xf = (float*)alloc((size_t)BTv * Dv * 4);
    short* xb = (short*)alloc((size_t)BTv * Dv * 2);
    short* xbT = (short*)alloc((size_t)BTv * Dv * 2);
    short* xy = (short*)alloc((size_t)BHv * Tv * Nv * 2);
    short* qr = (short*)alloc((size_t)BHv * Tv * Nv * 2);
    short* scs = (short*)alloc((size_t)KS_SC * BHv * Tv * Tv * 2);   // score slabs (bf16)
    short* scb = (short*)alloc((size_t)BHv * Tv * Tv * 2);           // reduced masked scores
    short* ykvh = (short*)alloc((size_t)BHv * Tv * Dv * 2);          // pvg out (bf16)
    short* ykvb = (short*)alloc((size_t)BHv * Tv * Dv * 2);
    short* ymb = (short*)alloc((size_t)NHv * KS_DEC * BTv * Dv * 2); // decode slabs (bf16)
    if (off > ws_size) {
        fprintf(stderr, "BDH: workspace too small: need %zu, have %zu\n", off, ws_size);
        return;
    }

    // one-time prep (per call): bf16 transposed weights + rope table + x0
    k_cvtT<<<dim3(Nv / 32, Dv / 32, NHv), 256, 0, stream>>>(enc, encT, Dv, Nv);
    k_cvtT<<<dim3(Nv / 32, Dv / 32, NHv), 256, 0, stream>>>(encv, encvT, Dv, Nv);
    k_cvtT<<<dim3(Dv / 32, Nv / 32, NHv), 256, 0, stream>>>(dec, decT, Nv, Dv);
    k_cvtT<<<dim3(Vv / 32, Dv / 32, 1), 256, 0, stream>>>(lmh, lmhT, Dv, Vv);
    k_rope<<<dim3(Nv / 2 / 256, Tv), 256, 0, stream>>>(ropeT);
    k_embed_ln<<<BTv, 256, 0, stream>>>(idx, embed, xf, xb);

    for (int L = 0; L < NLv; L++) {
        k_latent<<<2048, 256, 0, stream>>>(xb, encT, ropeT, qr);
        k_transp<<<dim3(Tv / 32, Dv / 32, Bv), 256, 0, stream>>>(xb, xbT);
        k_scores<<<640, 256, 0, stream>>>(qr, scs);
        k_redsc<<<(BHv * Tv * Tv / 8) / 256, 256, 0, stream>>>(scs, scb);
        k_pvg<<<dim3(Tv / 128, Dv / 128, BHv), 256, 0, stream>>>(scb, xbT, ykvh);
        k_ln<<<BHv * Tv, 256, 0, stream>>>(ykvh, ykvb);
        k_gate<<<2048, 256, 0, stream>>>(ykvb, encvT, qr, ropeT, xy);
        k_decode<<<512, 256, 0, stream>>>(xy, decT, ymb);
        k_lnsum<<<BTv, 256, 0, stream>>>(ymb, xf, xb);
    }
    k_head<<<dim3(BTv / 128, Vv / 128), 256, 0, stream>>>(xb, lmhT, out);
}

// Round 20
// 756.662 us; speedup vs baseline: 1.2373x; 1.0090x over previous
//
#include <hip/hip_runtime.h>
#include <hip/hip_bf16.h>
#include <cstdio>

#define DEV static __device__ __forceinline__

typedef __attribute__((ext_vector_type(4))) float floatx4;
typedef __attribute__((ext_vector_type(8))) __bf16 bf16x8;

constexpr int Bv = 2, Tv = 512, Dv = 256, NHv = 4, Nv = 8192, NLv = 4, Vv = 256;
constexpr int BTv = Bv * Tv;   // 1024 rows (b,t)
constexpr int BHv = Bv * NHv;  // 8
constexpr float LNEPS = 1e-5f;
constexpr int KS_SC = 8;   // K-split for scores (K=8192 -> 1024 per block)
constexpr int KS_DEC = 8;  // K-split for decode (K=8192 -> 1024 per block)

DEV float b2f(short s) {
    unsigned u = ((unsigned)(unsigned short)s) << 16;
    return __builtin_bit_cast(float, u);
}
DEV short f2b(float f) {  // RNE f32 -> bf16
    unsigned u = __builtin_bit_cast(unsigned, f);
    u = (u + 0x7fffu + ((u >> 16) & 1u)) >> 16;
    return (short)u;
}

typedef __attribute__((address_space(3))) unsigned int lds_u32;
typedef const __attribute__((address_space(1))) unsigned int glb_u32;
// async global->LDS, 16B per lane, whole wave writes ldsbase + lane*16
DEV void gload16(const short* g, short* ldsbase) {
    __builtin_amdgcn_global_load_lds((glb_u32*)g, (lds_u32*)ldsbase, 16, 0, 0);
}

// ---------------- transpose + f32->bf16 convert: in (R,C) -> out (C,R), per batch z
__global__ __launch_bounds__(256) void k_cvtT(const float* __restrict__ in,
                                              short* __restrict__ out, int R, int C) {
    __shared__ float tile[32][33];
    const float* ib = in + (size_t)blockIdx.z * R * C;
    short* ob = out + (size_t)blockIdx.z * R * C;
    int c0 = blockIdx.x * 32, r0 = blockIdx.y * 32;
    int tx = threadIdx.x & 31, ty = threadIdx.x >> 5;  // 32 x 8
#pragma unroll
    for (int i = 0; i < 4; i++) {
        int r = r0 + ty + i * 8;
        tile[ty + i * 8][tx] = ib[(size_t)r * C + c0 + tx];
    }
    __syncthreads();
#pragma unroll
    for (int i = 0; i < 4; i++) {
        int c = c0 + ty + i * 8;
        ob[(size_t)c * R + r0 + tx] = f2b(tile[tx][ty + i * 8]);
    }
}

// ---------------- bf16 transpose: xb (B*T, D) -> xbT [b][d][t]
__global__ __launch_bounds__(256) void k_transp(const short* __restrict__ xb,
                                                short* __restrict__ xbT) {
    __shared__ short tile[32][33];
    int b = blockIdx.z;
    int t0 = blockIdx.x * 32, d0 = blockIdx.y * 32;
    int tx = threadIdx.x & 31, ty = threadIdx.x >> 5;
#pragma unroll
    for (int i = 0; i < 4; i++)
        tile[ty + i * 8][tx] = xb[((size_t)b * Tv + t0 + ty + i * 8) * Dv + d0 + tx];
    __syncthreads();
#pragma unroll
    for (int i = 0; i < 4; i++)
        xbT[((size_t)b * Dv + d0 + ty + i * 8) * Tv + t0 + tx] = tile[tx][ty + i * 8];
}

// ---------------- rope table: (t, pair i) -> packed (bf16 cos | bf16 sin<<16)
__global__ __launch_bounds__(256) void k_rope(unsigned* __restrict__ tab) {
    int i = blockIdx.x * 256 + threadIdx.x;  // pair index 0..4095
    int t = blockIdx.y;
    float f = exp2f(-(float)i / 256.0f) * 0.15915494309189535f;
    float ph = fmodf((float)t * f, 1.0f) * 6.2831853071795864f;
    unsigned c = (unsigned short)f2b(cosf(ph));
    unsigned s = (unsigned short)f2b(sinf(ph));
    tab[(size_t)t * (Nv / 2) + i] = c | (s << 16);
}

// ---------------- block reduce (256 threads = 4 waves)
DEV void reduce2(float& s1, float& s2) {
    __shared__ float r1[4];
    __shared__ float r2[4];
#pragma unroll
    for (int o = 32; o > 0; o >>= 1) {
        s1 += __shfl_down(s1, o, 64);
        s2 += __shfl_down(s2, o, 64);
    }
    int lane = threadIdx.x & 63, w = threadIdx.x >> 6;
    if (lane == 0) { r1[w] = s1; r2[w] = s2; }
    __syncthreads();
    s1 = r1[0] + r1[1] + r1[2] + r1[3];
    s2 = r2[0] + r2[1] + r2[2] + r2[3];
}

DEV float ln_val(float v, float s1, float s2) {
    float m = s1 * (1.0f / Dv);
    float var = s2 * (1.0f / Dv) - m * m;
    float inv = rsqrtf(var + LNEPS);
    return (v - m) * inv;
}

// ---------------- embed lookup + LN -> x_f32, x_bf16
__global__ __launch_bounds__(256) void k_embed_ln(const int* __restrict__ idx,
                                                  const float* __restrict__ embed,
                                                  float* __restrict__ xf, short* __restrict__ xb) {
    int r = blockIdx.x, d = threadIdx.x;
    float v = embed[(size_t)idx[r] * Dv + d];
    float s1 = v, s2 = v * v;
    reduce2(s1, s2);
    float o = ln_val(v, s1, s2);
    xf[(size_t)r * Dv + d] = o;
    xb[(size_t)r * Dv + d] = f2b(o);
}

// ---------------- LN over D, bf16 in -> bf16 out
__global__ __launch_bounds__(256) void k_ln(const short* __restrict__ in,
                                            short* __restrict__ outb) {
    int r = blockIdx.x, d = threadIdx.x;
    size_t o = (size_t)r * Dv + d;
    float v = b2f(in[o]);
    float s1 = v, s2 = v * v;
    reduce2(s1, s2);
    outb[o] = f2b(ln_val(v, s1, s2));
}

// ---------------- residual LN with 32-slab sum: x = LN(xf + sum_z ymb[z])
__global__ __launch_bounds__(256) void k_lnsum(const short* __restrict__ ymb,
                                               float* __restrict__ xf, short* __restrict__ xb) {
    int r = blockIdx.x, d = threadIdx.x;
    size_t o = (size_t)r * Dv + d;
    float v = xf[o];
#pragma unroll
    for (int z = 0; z < NHv * KS_DEC; z++)
        v += b2f(ymb[(size_t)z * BTv * Dv + o]);
    float s1 = v, s2 = v * v;
    reduce2(s1, s2);
    float res = ln_val(v, s1, s2);
    xf[o] = res;
    xb[o] = f2b(res);
}

// ---------------- MFMA 128x128 tile mainloop with global_load_lds staging.
// LDS layout [128][32] shorts, chunk-XOR swizzled: physical 16B-chunk cp of row r
// holds logical chunk cp ^ ((r>>1)&3).  Source-permute == read-permute (involution).
DEV void gemm_main(const short* __restrict__ Ab, int lda,
                   const short* __restrict__ Bb, int ldb, int K,
                   short* sA, short* sB, floatx4 acc[4][4]) {
    const int tid = threadIdx.x;
    const int lane = tid & 63, w = tid >> 6;
    const int wr = w >> 1, wc = w & 1;
    const int lrow = lane & 15;
    const int q = lane >> 4;                       // logical K-chunk of this lane
    const int rsw = (lrow >> 1) & 3;               // read swizzle selector
    const int srow = lane >> 2;                    // staged row within 16-row group
    const int ssw = (lane & 3) ^ ((lane >> 3) & 3);// staged logical chunk
    for (int kk = 0; kk < K; kk += 32) {
        __syncthreads();
#pragma unroll
        for (int g2 = 0; g2 < 2; g2++) {
            int brow = g2 * 64 + w * 16;           // wave-uniform base row
            int grow = brow + srow;
            gload16(&Ab[(size_t)grow * lda + kk + ssw * 8], &sA[brow * 32]);
            gload16(&Bb[(size_t)grow * ldb + kk + ssw * 8], &sB[brow * 32]);
        }
        __syncthreads();                           // drains vmcnt -> LDS ready
        bf16x8 aF[4], bF[4];
#pragma unroll
        for (int m = 0; m < 4; m++)
            aF[m] = *(const bf16x8*)&sA[(wr * 64 + m * 16 + lrow) * 32 + ((q ^ rsw) * 8)];
#pragma unroll
        for (int n = 0; n < 4; n++)
            bF[n] = *(const bf16x8*)&sB[(wc * 64 + n * 16 + lrow) * 32 + ((q ^ rsw) * 8)];
#pragma unroll
        for (int m = 0; m < 4; m++)
#pragma unroll
            for (int n = 0; n < 4; n++)
                acc[m][n] = __builtin_amdgcn_mfma_f32_16x16x32_bf16(aF[m], bF[n], acc[m][n], 0, 0, 0);
    }
}

// ---------------- layer GEMM 1 + fused rope: qr = rope(relu(x @ enc[h]))  (no xs write)
// XCD-aware: all 8 mb-blocks sharing a (nb,h) B-tile have same bid%8 -> same XCD L2.
__global__ __launch_bounds__(256) void k_latent(const short* __restrict__ xb,
                                                const short* __restrict__ encT,
                                                const unsigned* __restrict__ ropeT,
                                                short* __restrict__ qr) {
    __shared__ short sA[128 * 32];
    __shared__ short sB[128 * 32];
    int bid = blockIdx.x;                 // 2048 blocks
    int xcd = bid & 7, rr = bid >> 3;     // rr: 0..255
    int cmb = xcd + 8 * (rr & 31);        // (nb,h) combo 0..255, fixed per XCD
    int mb = rr >> 5;                     // 0..7
    int nb = cmb & 63, h = cmb >> 6;
    const short* Ab = xb + (size_t)mb * 128 * Dv;
    const short* Bb = encT + (size_t)h * Nv * Dv + (size_t)nb * 128 * Dv;
    floatx4 acc[4][4] = {};
    gemm_main(Ab, Dv, Bb, Dv, Dv, sA, sB, acc);
    int lane = threadIdx.x & 63, w = threadIdx.x >> 6, wr = w >> 1, wc = w & 1;
    int rb = (lane >> 4) * 4, cb = lane & 15;
    float sgn = (cb & 1) ? 1.0f : -1.0f;
#pragma unroll
    for (int m = 0; m < 4; m++)
#pragma unroll
        for (int n = 0; n < 4; n++) {
            int col = nb * 128 + wc * 64 + n * 16 + cb;
#pragma unroll
            for (int r = 0; r < 4; r++) {
                int row = mb * 128 + wr * 64 + m * 16 + rb + r;
                int b = row >> 9, t = row & 511;
                float v = acc[m][n][r];
                v = v > 0.f ? v : 0.f;
                float vp = __shfl_xor(v, 1);  // partner neuron in pair (cols 2i,2i+1)
                unsigned cs = ropeT[(size_t)t * (Nv / 2) + (col >> 1)];
                float c = b2f((short)(cs & 0xffff)), s = b2f((short)(cs >> 16));
                qr[((size_t)(b * NHv + h) * Tv + t) * Nv + col] = f2b(v * c + sgn * vp * s);
            }
        }
}

// ---------------- scores (K-split, slab output, NO atomics):
// scs[ks][bh][t][s] = partial qr[t,:].qr[s,:] over K-chunk ks, bf16
// XCD-aware: all 10 pb-blocks of one (bh,ks) share qr tiles on one XCD.
__global__ __launch_bounds__(256) void k_scores(const short* __restrict__ qr,
                                                short* __restrict__ scs) {
    __shared__ short sA[128 * 32];
    __shared__ short sB[128 * 32];
    int bid = blockIdx.x;                 // 640 blocks
    int xcd = bid & 7, rr = bid >> 3;     // rr: 0..79
    int cmb = xcd + 8 * (rr & 7);         // (bh,ks) combo 0..63
    int pb = rr >> 3;                     // 0..9
    int bh = cmb & 7, ks = cmb >> 3;
    int tb = 0;
    while (((tb + 1) * (tb + 2)) / 2 <= pb) tb++;
    int sb = pb - (tb * (tb + 1)) / 2;
    const bool diag = (tb == sb);
    const int KC = Nv / KS_SC;
    const short* Ab = qr + ((size_t)bh * Tv + tb * 128) * Nv + ks * KC;
    const short* Bb = qr + ((size_t)bh * Tv + sb * 128) * Nv + ks * KC;
    floatx4 acc[4][4] = {};
    const int tid = threadIdx.x, lane = tid & 63, w = tid >> 6;
    const int wr = w >> 1, wc = w & 1;
    const int lrow = lane & 15;
    const int q = lane >> 4;
    const int rsw = (lrow >> 1) & 3;
    const int srow = lane >> 2;
    const int ssw = (lane & 3) ^ ((lane >> 3) & 3);
    for (int kk = 0; kk < KC; kk += 32) {
        __syncthreads();
#pragma unroll
        for (int g2 = 0; g2 < 2; g2++) {
            int brow = g2 * 64 + w * 16;
            int grow = brow + srow;
            gload16(&Ab[(size_t)grow * Nv + kk + ssw * 8], &sA[brow * 32]);
            if (!diag)
                gload16(&Bb[(size_t)grow * Nv + kk + ssw * 8], &sB[brow * 32]);
        }
        __syncthreads();
        const short* sBr = diag ? sA : sB;
        bf16x8 aF[4], bF[4];
#pragma unroll
        for (int m = 0; m < 4; m++)
            aF[m] = *(const bf16x8*)&sA[(wr * 64 + m * 16 + lrow) * 32 + ((q ^ rsw) * 8)];
#pragma unroll
        for (int n = 0; n < 4; n++)
            bF[n] = *(const bf16x8*)&sBr[(wc * 64 + n * 16 + lrow) * 32 + ((q ^ rsw) * 8)];
#pragma unroll
        for (int m = 0; m < 4; m++)
#pragma unroll
            for (int n = 0; n < 4; n++)
                acc[m][n] = __builtin_amdgcn_mfma_f32_16x16x32_bf16(aF[m], bF[n], acc[m][n], 0, 0, 0);
    }
    short* slab = scs + ((size_t)ks * BHv + bh) * Tv * Tv;
    int rb = (lane >> 4) * 4, cb = lane & 15;
#pragma unroll
    for (int m = 0; m < 4; m++)
#pragma unroll
        for (int n = 0; n < 4; n++)
#pragma unroll
            for (int r = 0; r < 4; r++) {
                int t = tb * 128 + wr * 64 + m * 16 + rb + r;
                int s = sb * 128 + wc * 64 + n * 16 + cb;
                slab[(size_t)t * Tv + s] = f2b(acc[m][n][r]);
            }
}

// ---------------- sum slabs + strict-lower mask -> scb (bf16); causal chunk skip
__global__ __launch_bounds__(256) void k_redsc(const short* __restrict__ scs,
                                               short* __restrict__ scb) {
    int c = blockIdx.x * 256 + threadIdx.x;  // one 8-elem chunk
    int row = c >> 6;                        // bh*512 + t
    int s0 = (c & 63) * 8;
    int t = row & (Tv - 1);
    union { short s[8]; int4 v; } u;
    if (s0 >= t) {
        // whole chunk masked: skip all slab loads
        u.v = make_int4(0, 0, 0, 0);
    } else {
        float a[8] = {};
#pragma unroll
        for (int ks = 0; ks < KS_SC; ks++) {
            int4 raw = *(const int4*)&scs[((size_t)ks * BHv * Tv + row) * Tv + s0];
            const short* rs = (const short*)&raw;
#pragma unroll
            for (int j = 0; j < 8; j++) a[j] += b2f(rs[j]);
        }
#pragma unroll
        for (int j = 0; j < 8; j++) u.s[j] = (s0 + j < t) ? f2b(a[j]) : 0;
    }
    *(int4*)&scb[(size_t)row * Tv + s0] = u.v;
}

// ---------------- yKV = scb @ V via MFMA.  A = scb (bf16), B^T = xbT.
// Causal trim: scb upper-tri is zero, so K-loop stops at (mb+1)*128.  Writes bf16.
__global__ __launch_bounds__(256) void k_pvg(const short* __restrict__ scb,
                                             const short* __restrict__ xbT,
                                             short* __restrict__ ykvh) {
    __shared__ short sA[128 * 32];
    __shared__ short sB[128 * 32];
    int mb = blockIdx.x, nb = blockIdx.y, bh = blockIdx.z;
    int b = bh >> 2;
    const short* Ab = scb + ((size_t)bh * Tv + mb * 128) * Tv;
    const short* Bb = xbT + ((size_t)b * Dv + nb * 128) * Tv;
    floatx4 acc[4][4] = {};
    gemm_main(Ab, Tv, Bb, Tv, (mb + 1) * 128, sA, sB, acc);
    int lane = threadIdx.x & 63, w = threadIdx.x >> 6, wr = w >> 1, wc = w & 1;
    int rb = (lane >> 4) * 4, cb = lane & 15;
#pragma unroll
    for (int m = 0; m < 4; m++)
#pragma unroll
        for (int n = 0; n < 4; n++)
#pragma unroll
            for (int r = 0; r < 4; r++) {
                int t = mb * 128 + wr * 64 + m * 16 + rb + r;
                int d = nb * 128 + wc * 64 + n * 16 + cb;
                ykvh[((size_t)bh * Tv + t) * Dv + d] = f2b(acc[m][n][r]);
            }
}

// ---------------- GEMM2 + gate: xy = relu(yKV_ln @ encv[h]) * invrope(qr)
// XCD-aware: all 8 (mb,b)-blocks sharing a (nb,h) encvT tile on one XCD.
__global__ __launch_bounds__(256) void k_gate(const short* __restrict__ ykvb,
                                              const short* __restrict__ encvT,
                                              const short* __restrict__ qr,
                                              const unsigned* __restrict__ ropeT,
                                              short* __restrict__ xy) {
    __shared__ short sA[128 * 32];
    __shared__ short sB[128 * 32];
    int bid = blockIdx.x;                 // 2048 blocks
    int xcd = bid & 7, rr = bid >> 3;     // rr: 0..255
    int cmb = xcd + 8 * (rr & 31);        // (nb,h) combo 0..255
    int wi = rr >> 5;                     // 0..7 = (mb,b)
    int mb = wi & 3, bq = wi >> 2;
    int nb = cmb & 63, h = cmb >> 6;
    int bh = bq * NHv + h;
    const short* Ab = ykvb + ((size_t)bh * Tv + mb * 128) * Dv;
    const short* Bb = encvT + (size_t)h * Nv * Dv + (size_t)nb * 128 * Dv;
    floatx4 acc[4][4] = {};
    gemm_main(Ab, Dv, Bb, Dv, Dv, sA, sB, acc);
    int lane = threadIdx.x & 63, w = threadIdx.x >> 6, wr = w >> 1, wc = w & 1;
    int rb = (lane >> 4) * 4, cb = lane & 15;
    int par = cb & 1;
    float sgn = par ? 1.0f : -1.0f;
#pragma unroll
    for (int m = 0; m < 4; m++)
#pragma unroll
        for (int n = 0; n < 4; n++) {
            int col = nb * 128 + wc * 64 + n * 16 + cb;
#pragma unroll
            for (int r = 0; r < 4; r++) {
                int t = mb * 128 + wr * 64 + m * 16 + rb + r;
                size_t idx = ((size_t)bh * Tv + t) * Nv + col;
                unsigned pq = *(const unsigned*)&qr[idx & ~(size_t)1];  // (even,odd) pair in one 4B load
                float qlo = b2f((short)(pq & 0xffff)), qhi2 = b2f((short)(pq >> 16));
                float qv = par ? qhi2 : qlo;
                float qp = par ? qlo : qhi2;
                unsigned cs = ropeT[(size_t)t * (Nv / 2) + (col >> 1)];
                float c = b2f((short)(cs & 0xffff)), s = b2f((short)(cs >> 16));
                float xsr = qv * c - sgn * qp * s;  // inverse rotation = x_sparse
                float v = acc[m][n][r];
                v = v > 0.f ? v : 0.f;
                xy[idx] = f2b(v * xsr);
            }
        }
}

// ---------------- decode (K-split=8, slab output, NO atomics):
// ymb[z=(h*KS+ks)][row][d] = partial xy[h] @ dec[h], bf16
// XCD-aware: 8 mb-blocks sharing a (nb,h,ks) decT panel on one XCD.  512 blocks.
__global__ __launch_bounds__(256) void k_decode(const short* __restrict__ xy,
                                                const short* __restrict__ decT,
                                                short* __restrict__ ymb) {
    __shared__ short sA[128 * 32];
    __shared__ short sB[128 * 32];
    int bid = blockIdx.x;                 // 512 blocks
    int xcd = bid & 7, rr = bid >> 3;     // rr: 0..63
    int cmb = xcd + 8 * (rr & 7);         // (nb,h,ks) combo 0..63
    int mb = rr >> 3;                     // 0..7
    int nb = cmb & 1, h = (cmb >> 1) & 3, ks = cmb >> 3;
    const int KC = Nv / KS_DEC;           // 1024
    int row0 = mb * 128;
    int b = row0 >> 9, t0 = row0 & 511;
    const short* Ab = xy + ((size_t)(b * NHv + h) * Tv + t0) * Nv + ks * KC;
    const short* Bb = decT + (size_t)h * Dv * Nv + (size_t)nb * 128 * Nv + ks * KC;
    floatx4 acc[4][4] = {};
    gemm_main(Ab, Nv, Bb, Nv, KC, sA, sB, acc);
    short* slab = ymb + (size_t)(h * KS_DEC + ks) * BTv * Dv;
    int lane = threadIdx.x & 63, w = threadIdx.x >> 6, wr = w >> 1, wc = w & 1;
    int rb = (lane >> 4) * 4, cb = lane & 15;
#pragma unroll
    for (int m = 0; m < 4; m++)
#pragma unroll
        for (int n = 0; n < 4; n++)
#pragma unroll
            for (int r = 0; r < 4; r++) {
                int row = row0 + wr * 64 + m * 16 + rb + r;
                int col = nb * 128 + wc * 64 + n * 16 + cb;
                slab[(size_t)row * Dv + col] = f2b(acc[m][n][r]);
            }
}

// ---------------- final head: out = x @ lm_head
__global__ __launch_bounds__(256) void k_head(const short* __restrict__ xb,
                                              const short* __restrict__ lmhT,
                                              float* __restrict__ out) {
    __shared__ short sA[128 * 32];
    __shared__ short sB[128 * 32];
    int mb = blockIdx.x, nb = blockIdx.y;
    const short* Ab = xb + (size_t)mb * 128 * Dv;
    const short* Bb = lmhT + (size_t)nb * 128 * Dv;
    floatx4 acc[4][4] = {};
    gemm_main(Ab, Dv, Bb, Dv, Dv, sA, sB, acc);
    int lane = threadIdx.x & 63, w = threadIdx.x >> 6, wr = w >> 1, wc = w & 1;
    int rb = (lane >> 4) * 4, cb = lane & 15;
#pragma unroll
    for (int m = 0; m < 4; m++)
#pragma unroll
        for (int n = 0; n < 4; n++)
#pragma unroll
            for (int r = 0; r < 4; r++) {
                int row = mb * 128 + wr * 64 + m * 16 + rb + r;
                int col = nb * 128 + wc * 64 + n * 16 + cb;
                out[(size_t)row * Vv + col] = acc[m][n][r];
            }
}

extern "C" void kernel_launch(void* const* d_in, const int* in_sizes, int n_in,
                              void* d_out, int out_size, void* d_ws, size_t ws_size,
                              hipStream_t stream) {
    const int* idx = (const int*)d_in[0];
    const float* embed = (const float*)d_in[1];
    const float* enc = (const float*)d_in[2];
    const float* encv = (const float*)d_in[3];
    const float* dec = (const float*)d_in[4];
    const float* lmh = (const float*)d_in[5];
    float* out = (float*)d_out;

    char* w = (char*)d_ws;
    size_t off = 0;
    auto alloc = [&](size_t bytes) -> void* {
        void* p = w + off;
        off = (off + bytes + 255) & ~(size_t)255;
        return p;
    };
    short* encT = (short*)alloc((size_t)NHv * Nv * Dv * 2);
    short* encvT = (short*)alloc((size_t)NHv * Nv * Dv * 2);
    short* decT = (short*)alloc((size_t)NHv * Dv * Nv * 2);
    short* lmhT = (short*)alloc((size_t)Vv * Dv * 2);
    unsigned* ropeT = (unsigned*)alloc((size_t)Tv * (Nv / 2) * 4);
    float* xf = (float*)alloc((size_t)BTv * Dv * 4);
    short* xb = (short*)alloc((size_t)BTv * Dv * 2);
    short* xbT = (short*)alloc((size_t)BTv * Dv * 2);
    short* xy = (short*)alloc((size_t)BHv * Tv * Nv * 2);
    short* qr = (short*)alloc((size_t)BHv * Tv * Nv * 2);
    short* scs = (short*)alloc((size_t)KS_SC * BHv * Tv * Tv * 2);   // score slabs (bf16)
    short* scb = (short*)alloc((size_t)BHv * Tv * Tv * 2);           // reduced masked scores
    short* ykvh = (short*)alloc((size_t)BHv * Tv * Dv * 2);          // pvg out (bf16)
    short* ykvb = (short*)alloc((size_t)BHv * Tv * Dv * 2);
    short* ymb = (short*)alloc((size_t)NHv * KS_DEC * BTv * Dv * 2); // decode slabs (bf16)
    if (off > ws_size) {
        fprintf(stderr, "BDH: workspace too small: need %zu, have %zu\n", off, ws_size);
        return;
    }

    // one-time prep (per call): bf16 transposed weights + rope table + x0
    k_cvtT<<<dim3(Nv / 32, Dv / 32, NHv), 256, 0, stream>>>(enc, encT, Dv, Nv);
    k_cvtT<<<dim3(Nv / 32, Dv / 32, NHv), 256, 0, stream>>>(encv, encvT, Dv, Nv);
    k_cvtT<<<dim3(Dv / 32, Nv / 32, NHv), 256, 0, stream>>>(dec, decT, Nv, Dv);
    k_cvtT<<<dim3(Vv / 32, Dv / 32, 1), 256, 0, stream>>>(lmh, lmhT, Dv, Vv);
    k_rope<<<dim3(Nv / 2 / 256, Tv), 256, 0, stream>>>(ropeT);
    k_embed_ln<<<BTv, 256, 0, stream>>>(idx, embed, xf, xb);

    for (int L = 0; L < NLv; L++) {
        k_latent<<<2048, 256, 0, stream>>>(xb, encT, ropeT, qr);
        k_transp<<<dim3(Tv / 32, Dv / 32, Bv), 256, 0, stream>>>(xb, xbT);
        k_scores<<<640, 256, 0, stream>>>(qr, scs);
        k_redsc<<<(BHv * Tv * Tv / 8) / 256, 256, 0, stream>>>(scs, scb);
        k_pvg<<<dim3(Tv / 128, Dv / 128, BHv), 256, 0, stream>>>(scb, xbT, ykvh);
        k_ln<<<BHv * Tv, 256, 0, stream>>>(ykvh, ykvb);
        k_gate<<<2048, 256, 0, stream>>>(ykvb, encvT, qr, ropeT, xy);
        k_decode<<<512, 256, 0, stream>>>(xy, decT, ymb);
        k_lnsum<<<BTv, 256, 0, stream>>>(ymb, xf, xb);
    }
    k_head<<<dim3(BTv / 128, Vv / 128), 256, 0, stream>>>(xb, lmhT, out);
}